// Round 7
// baseline (128.207 us; speedup 1.0000x reference)
//
#include <hip/hip_runtime.h>
#include <math.h>

// Problem constants: N=128 features, H=256 hidden, B=16 batch.
//
// Analytic collapse of the reference:
//   S = W1^T W1  [256x256] (symmetric), Q = W2 W2^T [256x256] (symmetric)
//   per sample: d = 1-tanh^2(h), c = -2 z d,  P = S diag(d) W2  [256x128]
//   ||dG||_F^2 = 2 sum_{m,m'} c_m c_m' S[m,m'] ( Q[m,m'] R[m,m'] + M[m,m'] M[m',m] )
//        R = P P^T, M = P W2^T
//   Gamma contraction = 0.5*( W2^T (c .* Pv .* Uv) + P^T (c .* W2v .* Uv) )
//
// R4 lesson: grid.sync() ~35us each -> separate launches.
// R5 lesson: single-wave L2-streaming fnorm is latency-bound -> LDS staging.
// R6 lesson: harness fixed cost ~82us; kernels+gaps ~42us. R3's fusion loss
//   was the stride-48 (=16 mod 32) scratch -> 32-way bank conflict; fixed
//   with stride 49. This round: fin fused into fnorm via last-arrival block.

// ws layout (float offsets)
static constexpr int OFF_W2T  = 0;        // [128][256]
static constexpr int OFF_S    = 32768;    // [256][256]
static constexpr int OFF_Q    = 98304;    // [256][256]
static constexpr int OFF_D    = 163840;   // [16][256]
static constexpr int OFF_C    = 167936;   // [16][256]
static constexpr int OFF_UV   = 172032;   // [16][256]
static constexpr int OFF_AV   = 176128;   // [16][256]
static constexpr int OFF_VN   = 180224;   // [16]
static constexpr int OFF_SUM  = 180240;   // [16] float accumulator (fnorm^2/2)
static constexpr int OFF_CNT  = 180256;   // [16] int arrival counters
static constexpr int OFF_PT   = 180288;   // [16][128][256]  PT[b][j][m] = P[b][m][j]
static constexpr int OFF_PN   = OFF_PT + 16 * 32768;  // [16][256][128] row-major P
// total ~= 1228864 floats ~= 4.9 MB

// =====================================================================
// Stage 1 (176 blocks x 256 thr):
//   blocks   0..63 : S = W1^T W1
//   blocks  64..127: Q = W2 W2^T
//   blocks 128..159: W2T transpose
//   blocks 160..175: per-sample prep (+ zero SUM/CNT, out rows 0..15)
// =====================================================================
__global__ __launch_bounds__(256) void k_stage1(const float* __restrict__ tptr,
                                                const float* __restrict__ state,
                                                const float* __restrict__ x0,
                                                const float* __restrict__ x1,
                                                const float* __restrict__ W1,
                                                const float* __restrict__ b1,
                                                const float* __restrict__ W2,
                                                float* __restrict__ ws,
                                                float* __restrict__ out) {
    __shared__ __align__(16) float smem[2 * 32 * 34];
    int blk = blockIdx.x;
    int tid = threadIdx.x;

    if (blk < 64) {
        // ---- S[m,n] = sum_k W1[k,m] W1[k,n], W1 is [128][256] ----
        float* Ai = smem;            // [32][34] : [k][m]
        float* Aj = smem + 1088;
        int m0 = (blk >> 3) * 32, n0 = (blk & 7) * 32;
        int lx = tid & 31, lr = tid >> 5;
        int tx = tid & 15, ty = tid >> 4;
        float a00 = 0, a01 = 0, a10 = 0, a11 = 0;
        for (int kc = 0; kc < 128; kc += 32) {
            #pragma unroll
            for (int i = 0; i < 4; ++i) {
                int k = lr + 8 * i;
                Ai[k * 34 + lx] = W1[(kc + k) * 256 + m0 + lx];
                Aj[k * 34 + lx] = W1[(kc + k) * 256 + n0 + lx];
            }
            __syncthreads();
            #pragma unroll
            for (int k = 0; k < 32; ++k) {
                float2 a = *(const float2*)&Ai[k * 34 + 2 * ty];
                float2 b = *(const float2*)&Aj[k * 34 + 2 * tx];
                a00 += a.x * b.x; a01 += a.x * b.y;
                a10 += a.y * b.x; a11 += a.y * b.y;
            }
            __syncthreads();
        }
        float* S = ws + OFF_S;
        int m = m0 + 2 * ty, n = n0 + 2 * tx;
        S[m * 256 + n]           = a00;
        S[m * 256 + n + 1]       = a01;
        S[(m + 1) * 256 + n]     = a10;
        S[(m + 1) * 256 + n + 1] = a11;
    } else if (blk < 128) {
        // ---- Q[m,n] = sum_j W2[m,j] W2[n,j], W2 is [256][128] ----
        float* Xi = smem;            // [32][34] : [j][m]
        float* Xj = smem + 1088;
        int bq = blk - 64;
        int m0 = (bq >> 3) * 32, n0 = (bq & 7) * 32;
        int lx = tid & 31, lr = tid >> 5;
        int tx = tid & 15, ty = tid >> 4;
        float a00 = 0, a01 = 0, a10 = 0, a11 = 0;
        for (int kc = 0; kc < 128; kc += 32) {
            #pragma unroll
            for (int i = 0; i < 4; ++i) {
                Xi[lx * 34 + lr + 8 * i] = W2[(m0 + lr + 8 * i) * 128 + kc + lx];
                Xj[lx * 34 + lr + 8 * i] = W2[(n0 + lr + 8 * i) * 128 + kc + lx];
            }
            __syncthreads();
            #pragma unroll
            for (int k = 0; k < 32; ++k) {
                float2 a = *(const float2*)&Xi[k * 34 + 2 * ty];
                float2 b = *(const float2*)&Xj[k * 34 + 2 * tx];
                a00 += a.x * b.x; a01 += a.x * b.y;
                a10 += a.y * b.x; a11 += a.y * b.y;
            }
            __syncthreads();
        }
        float* Q = ws + OFF_Q;
        int m = m0 + 2 * ty, n = n0 + 2 * tx;
        Q[m * 256 + n]           = a00;
        Q[m * 256 + n + 1]       = a01;
        Q[(m + 1) * 256 + n]     = a10;
        Q[(m + 1) * 256 + n + 1] = a11;
    } else if (blk < 160) {
        // ---- W2T[c][r] = W2[r][c] ----
        float* tile = smem;  // [32][33]
        int b2 = blk - 128;
        int c0 = (b2 & 3) * 32, r0 = (b2 >> 2) * 32;
        int tx = tid & 31, ty = tid >> 5;
        #pragma unroll
        for (int i = 0; i < 32; i += 8)
            tile[(ty + i) * 33 + tx] = W2[(r0 + ty + i) * 128 + c0 + tx];
        __syncthreads();
        float* W2T = ws + OFF_W2T;
        #pragma unroll
        for (int i = 0; i < 32; i += 8)
            W2T[(c0 + ty + i) * 256 + r0 + tx] = tile[tx * 33 + ty + i];
    } else {
        // ---- per-sample prep ----
        int b = blk - 160;
        float* xs  = smem;
        float* vs  = smem + 128;
        float* red = smem + 256;
        float t = tptr[0];
        float w = 4.f * t * (1.f - t);
        if (tid == 0) {
            ws[OFF_SUM + b] = 0.f;
            ((int*)(ws + OFF_CNT))[b] = 0;
        }
        if (tid < 128) {
            float dev = state[b * 128 + tid];
            float v   = state[(16 + b) * 128 + tid];
            float xv  = x0[b * 128 + tid] + t * (x1[b * 128 + tid] - x0[b * 128 + tid]) + w * dev;
            xs[tid] = xv;
            vs[tid] = v;
            out[b * 128 + tid] = v;   // first-half output = dev_velocity
            red[tid] = v * v;
        }
        __syncthreads();
        for (int s = 64; s > 0; s >>= 1) {
            if (tid < s) red[tid] += red[tid + s];
            __syncthreads();
        }
        if (tid == 0) ws[OFF_VN + b] = sqrtf(red[0]);

        int m = tid;  // 0..255
        float h = b1[m], uvm = 0.f;
        #pragma unroll 8
        for (int k = 0; k < 128; ++k) {
            float wv = W1[k * 256 + m];    // coalesced
            h   += xs[k] * wv;
            uvm += vs[k] * wv;
        }
        float z  = tanhf(h);
        float dd = 1.f - z * z;
        float cc = -2.f * z * dd;
        const float4* w2r = (const float4*)&W2[m * 128];
        const float4* vs4 = (const float4*)vs;
        float avm = 0.f;
        #pragma unroll 8
        for (int j4 = 0; j4 < 32; ++j4) {
            float4 ww = w2r[j4];
            float4 vv = vs4[j4];
            avm += ww.x * vv.x + ww.y * vv.y + ww.z * vv.z + ww.w * vv.w;
        }
        ws[OFF_D  + b * 256 + m] = dd;
        ws[OFF_C  + b * 256 + m] = cc;
        ws[OFF_UV + b * 256 + m] = uvm;
        ws[OFF_AV + b * 256 + m] = avm;
    }
}

// =====================================================================
// P = S diag(d) W2. 256-thr blocks, 32m x 64j tile, 4x2 per thread.
// grid (2 jt, 8 mt, 16 b). Writes PT[b][j][m] and Pn[b][m][j].
// =====================================================================
__global__ __launch_bounds__(256) void k_pmat3(const float* __restrict__ Smat,
                                               const float* __restrict__ dall,
                                               const float* __restrict__ W2,
                                               float* __restrict__ PT,
                                               float* __restrict__ Pn) {
    __shared__ __align__(16) float ST[32 * 36];  // [n][m-local]
    __shared__ __align__(16) float YT[32 * 68];  // [n][j-local]
    int b = blockIdx.z, mt = blockIdx.y, jt = blockIdx.x;
    int m0 = mt * 32, j0 = jt * 64;
    const float* dvec = dall + b * 256;
    int tid = threadIdx.x;
    int n = tid >> 3, c4 = (tid & 7) * 4;    // staging
    int ty = tid >> 5, tx = tid & 31;        // compute: 4m x 2j
    float acc[4][2] = {};
    for (int nc = 0; nc < 256; nc += 32) {
        // S symmetric: S[m,n] = S[n,m] -> coalesced row reads
        *(float4*)&ST[n * 36 + c4] = *(const float4*)&Smat[(nc + n) * 256 + m0 + c4];
        float dn = dvec[nc + n];
        #pragma unroll
        for (int i = 0; i < 2; ++i) {
            int col = c4 + 32 * i;
            float4 wv = *(const float4*)&W2[(nc + n) * 128 + j0 + col];
            wv.x *= dn; wv.y *= dn; wv.z *= dn; wv.w *= dn;
            *(float4*)&YT[n * 68 + col] = wv;
        }
        __syncthreads();
        #pragma unroll 8
        for (int k = 0; k < 32; ++k) {
            float4 a  = *(const float4*)&ST[k * 36 + 4 * ty];
            float2 bb = *(const float2*)&YT[k * 68 + 2 * tx];
            acc[0][0] += a.x * bb.x; acc[0][1] += a.x * bb.y;
            acc[1][0] += a.y * bb.x; acc[1][1] += a.y * bb.y;
            acc[2][0] += a.z * bb.x; acc[2][1] += a.z * bb.y;
            acc[3][0] += a.w * bb.x; acc[3][1] += a.w * bb.y;
        }
        __syncthreads();
    }
    float* ptb = PT + b * 32768;
    float* pnb = Pn + b * 32768;
    #pragma unroll
    for (int jj = 0; jj < 2; ++jj) {
        float4 v = make_float4(acc[0][jj], acc[1][jj], acc[2][jj], acc[3][jj]);
        *(float4*)&ptb[(j0 + 2 * tx + jj) * 256 + m0 + 4 * ty] = v;
    }
    #pragma unroll
    for (int ii = 0; ii < 4; ++ii) {
        float2 v = make_float2(acc[ii][0], acc[ii][1]);
        *(float2*)&pnb[(m0 + 4 * ty + ii) * 128 + j0 + 2 * tx] = v;
    }
}

// =====================================================================
// Frobenius-norm partials + fused per-sample epilogue (last-arrival).
// 256-thr blocks (4 waves split j=128), triangular (mi,mj) tiles,
// grid (36,16). LDS-staged; stride-49 conflict-free reduction scratch.
// =====================================================================
__global__ __launch_bounds__(256) void k_fnorm6(const float* __restrict__ PT,
                                                const float* __restrict__ Pn,
                                                const float* __restrict__ W2T,
                                                const float* __restrict__ Smat,
                                                const float* __restrict__ Qmat,
                                                const float* __restrict__ state,
                                                const float* __restrict__ W2,
                                                float* __restrict__ ws,
                                                float* __restrict__ out) {
    __shared__ __align__(16) float lds[16384];  // 64 KB, re-purposed
    __shared__ int lastflag;
    __shared__ float snrm;
    int b = blockIdx.y;
    int idx = blockIdx.x;
    int tj = 0;
    while ((tj + 1) * (tj + 2) / 2 <= idx) ++tj;
    int ti = idx - tj * (tj + 1) / 2;      // ti <= tj
    int mi0 = ti * 32, mj0 = tj * 32;
    int tid = threadIdx.x;
    float* PiT = lds;              // [128][32]
    float* PjT = lds + 4096;
    float* WiT = lds + 8192;
    float* WjT = lds + 12288;
    const float* ptb = PT + b * 32768;
    int jr = tid >> 3, jc4 = (tid & 7) * 4;
    #pragma unroll
    for (int it = 0; it < 4; ++it) {
        int j = jr + 32 * it;
        *(float4*)&PiT[j * 32 + jc4] = *(const float4*)&ptb[j * 256 + mi0 + jc4];
        *(float4*)&PjT[j * 32 + jc4] = *(const float4*)&ptb[j * 256 + mj0 + jc4];
        *(float4*)&WiT[j * 32 + jc4] = *(const float4*)&W2T[j * 256 + mi0 + jc4];
        *(float4*)&WjT[j * 32 + jc4] = *(const float4*)&W2T[j * 256 + mj0 + jc4];
    }
    __syncthreads();
    int w = tid >> 6, s = tid & 63;
    int ty = s >> 3, tx = s & 7;
    float r[4][4] = {}, f[4][4] = {}, g[4][4] = {};
    int jbase = 32 * w;
    #pragma unroll 4
    for (int jj = 0; jj < 32; ++jj) {
        int j = jbase + jj;
        float4 pi4 = *(const float4*)&PiT[j * 32 + 4 * ty];
        float4 pj4 = *(const float4*)&PjT[j * 32 + 4 * tx];
        float4 wi4 = *(const float4*)&WiT[j * 32 + 4 * ty];
        float4 wj4 = *(const float4*)&WjT[j * 32 + 4 * tx];
        float pi[4] = {pi4.x, pi4.y, pi4.z, pi4.w};
        float pj[4] = {pj4.x, pj4.y, pj4.z, pj4.w};
        float wi[4] = {wi4.x, wi4.y, wi4.z, wi4.w};
        float wj[4] = {wj4.x, wj4.y, wj4.z, wj4.w};
        #pragma unroll
        for (int ii = 0; ii < 4; ++ii)
            #pragma unroll
            for (int kk = 0; kk < 4; ++kk) {
                r[ii][kk] += pi[ii] * pj[kk];   // R[mi,mj]
                f[ii][kk] += pi[ii] * wj[kk];   // M[mi,mj]
                g[ii][kk] += pj[kk] * wi[ii];   // M[mj,mi]
            }
    }
    __syncthreads();   // done with tiles; alias lds as reduction scratch
    {
        // stride 49 (odd) -> (tid*49+k) mod 32 covers all banks; <=2 lanes/bank
        float* scr = lds;
        int base = tid * 49;
        #pragma unroll
        for (int ii = 0; ii < 4; ++ii)
            #pragma unroll
            for (int kk = 0; kk < 4; ++kk) {
                scr[base + ii * 4 + kk]      = r[ii][kk];
                scr[base + 16 + ii * 4 + kk] = f[ii][kk];
                scr[base + 32 + ii * 4 + kk] = g[ii][kk];
            }
    }
    __syncthreads();
    if (tid < 64) {
        const float* scr = lds;
        float tr[16], tf[16], tg[16];
        #pragma unroll
        for (int k = 0; k < 16; ++k) {
            tr[k] = scr[tid * 49 + k]           + scr[(tid + 64) * 49 + k]
                  + scr[(tid + 128) * 49 + k]   + scr[(tid + 192) * 49 + k];
            tf[k] = scr[tid * 49 + 16 + k]      + scr[(tid + 64) * 49 + 16 + k]
                  + scr[(tid + 128) * 49 + 16 + k] + scr[(tid + 192) * 49 + 16 + k];
            tg[k] = scr[tid * 49 + 32 + k]      + scr[(tid + 64) * 49 + 32 + k]
                  + scr[(tid + 128) * 49 + 32 + k] + scr[(tid + 192) * 49 + 32 + k];
        }
        const float* cb = ws + OFF_C + b * 256;
        int mi = mi0 + 4 * (tid >> 3), mj = mj0 + 4 * (tid & 7);
        float4 ce4 = *(const float4*)&cb[mj];
        float ce[4] = {ce4.x, ce4.y, ce4.z, ce4.w};
        float sum = 0.f;
        #pragma unroll
        for (int ii = 0; ii < 4; ++ii) {
            float ci = cb[mi + ii];
            float4 S4 = *(const float4*)&Smat[(mi + ii) * 256 + mj];
            float4 Q4 = *(const float4*)&Qmat[(mi + ii) * 256 + mj];
            float Sv[4] = {S4.x, S4.y, S4.z, S4.w};
            float Qv[4] = {Q4.x, Q4.y, Q4.z, Q4.w};
            #pragma unroll
            for (int kk = 0; kk < 4; ++kk)
                sum += ci * ce[kk] * Sv[kk] * (Qv[kk] * tr[ii * 4 + kk] + tf[ii * 4 + kk] * tg[ii * 4 + kk]);
        }
        if (ti < tj) sum *= 2.f;
        #pragma unroll
        for (int off = 32; off > 0; off >>= 1)
            sum += __shfl_down(sum, off);
        if (tid == 0) {
            atomicAdd(&ws[OFF_SUM + b], sum);
            __threadfence();
            int old = atomicAdd(((int*)(ws + OFF_CNT)) + b, 1);
            lastflag = (old == 35) ? 1 : 0;
        }
    }
    __syncthreads();
    if (!lastflag) return;

    // ===== per-sample epilogue (exactly one block per sample) =====
    float* vs  = lds;          // [128]
    float* g1  = lds + 128;    // [256]
    float* g2  = lds + 384;    // [256]
    float* red = lds + 640;    // [256]
    if (tid == 0) {
        float tot = atomicAdd(&ws[OFF_SUM + b], 0.0f);  // coherent read
        snrm = sqrtf(fmaxf(2.f * tot, 0.f));
    }
    if (tid < 128) vs[tid] = state[(16 + b) * 128 + tid];
    __syncthreads();
    const float* pnb = Pn + b * 32768;
    int m = tid;
    float pv = 0.f;
    #pragma unroll 8
    for (int j = 0; j < 128; ++j)
        pv += ptb[j * 256 + m] * vs[j];     // coalesced over m
    float cc  = ws[OFF_C  + b * 256 + m];
    float uvm = ws[OFF_UV + b * 256 + m];
    float avm = ws[OFF_AV + b * 256 + m];
    g1[m] = cc * pv  * uvm;
    g2[m] = cc * avm * uvm;
    __syncthreads();
    int i = tid & 127, half = tid >> 7;
    int mmlo = half * 128;
    float raw = 0.f;
    #pragma unroll 8
    for (int mm = mmlo; mm < mmlo + 128; ++mm)
        raw += W2[mm * 128 + i] * g1[mm] + pnb[mm * 128 + i] * g2[mm];  // both coalesced
    red[tid] = raw;
    __syncthreads();
    if (tid < 128) {
        float rawt = red[tid] + red[tid + 128];
        float vn = ws[OFF_VN + b];
        float a  = -0.5f * rawt / ((snrm + 1e-6f) * (vn + 1e-6f));
        out[(16 + b) * 128 + tid] = a - 0.1f * state[b * 128 + tid];
    }
}

extern "C" void kernel_launch(void* const* d_in, const int* in_sizes, int n_in,
                              void* d_out, int out_size, void* d_ws, size_t ws_size,
                              hipStream_t stream) {
    (void)in_sizes; (void)n_in; (void)out_size; (void)ws_size;
    const float* t     = (const float*)d_in[0];
    const float* state = (const float*)d_in[1];
    const float* x0    = (const float*)d_in[2];
    const float* x1    = (const float*)d_in[3];
    const float* W1    = (const float*)d_in[4];
    const float* b1    = (const float*)d_in[5];
    const float* W2    = (const float*)d_in[6];
    // b2 cancels in the Jacobian — unused.
    float* out = (float*)d_out;
    float* ws  = (float*)d_ws;

    k_stage1<<<176, 256, 0, stream>>>(t, state, x0, x1, W1, b1, W2, ws, out);
    k_pmat3<<<dim3(2, 8, 16), 256, 0, stream>>>(ws + OFF_S, ws + OFF_D, W2,
                                                ws + OFF_PT, ws + OFF_PN);
    k_fnorm6<<<dim3(36, 16), 256, 0, stream>>>(ws + OFF_PT, ws + OFF_PN, ws + OFF_W2T,
                                               ws + OFF_S, ws + OFF_Q,
                                               state, W2, ws, out);
}

// Round 8
// 123.968 us; speedup vs baseline: 1.0342x; 1.0342x over previous
//
#include <hip/hip_runtime.h>
#include <math.h>

// Problem constants: N=128 features, H=256 hidden, B=16 batch.
//
// Analytic collapse of the reference:
//   S = W1^T W1  [256x256] (symmetric), Q = W2 W2^T [256x256] (symmetric)
//   per sample: d = 1-tanh^2(h), c = -2 z d,  P = S diag(d) W2  [256x128]
//   ||dG||_F^2 = 2 sum_{m,m'} c_m c_m' S[m,m'] ( Q[m,m'] R[m,m'] + M[m,m'] M[m',m] )
//        R = P P^T, M = P W2^T
//   Gamma contraction = 0.5*( W2^T (c .* Pv .* Uv) + P^T (c .* W2v .* Uv) )
//
// Session record (dur_us): R1 145.4 (7 kernels) -> R2 126.9 (4 kernels, reg
// tiling) -> R3 129.0 (fusion, bank-conflict bug) -> R4 218.5 (cooperative;
// grid.sync ~35us each) -> R5 171.9 (LDS-free fnorm: latency-bound) ->
// R6 124.3 (this structure) -> R7 128.2 (fusion retry, replicated loss).
// Lessons: (1) grid.sync is ~35us on MI355X - never worth it here.
// (2) Single-wave L2-streaming loops are latency-bound at low occupancy;
//     LDS staging + 4-wave blocks wins. (3) Last-arrival epilogue fusion
//     loses ~3us to tail serialization vs a separate 16-block launch
//     (replicated R3/R7). (4) Harness fixed cost ~82us (268MB ws re-poison
//     at ~80% HBM peak + input restores); kernel+gap budget ~42us.

// ws layout (float offsets)
static constexpr int OFF_W2T  = 0;        // [128][256]
static constexpr int OFF_S    = 32768;    // [256][256]
static constexpr int OFF_Q    = 98304;    // [256][256]
static constexpr int OFF_D    = 163840;   // [16][256]
static constexpr int OFF_C    = 167936;   // [16][256]
static constexpr int OFF_UV   = 172032;   // [16][256]
static constexpr int OFF_AV   = 176128;   // [16][256]
static constexpr int OFF_VN   = 180224;   // [16]
static constexpr int OFF_SUM  = 180240;   // [16] float accumulator (fnorm^2/2)
static constexpr int OFF_PT   = 180256;   // [16][128][256]  PT[b][j][m] = P[b][m][j]
static constexpr int OFF_PN   = OFF_PT + 16 * 32768;  // [16][256][128] row-major P
// total ~= 1228832 floats ~= 4.9 MB

// =====================================================================
// Stage 1 (176 blocks x 256 thr):
//   blocks   0..63 : S = W1^T W1
//   blocks  64..127: Q = W2 W2^T
//   blocks 128..159: W2T transpose
//   blocks 160..175: per-sample prep (+ zero SUM, out rows 0..15)
// =====================================================================
__global__ __launch_bounds__(256) void k_stage1(const float* __restrict__ tptr,
                                                const float* __restrict__ state,
                                                const float* __restrict__ x0,
                                                const float* __restrict__ x1,
                                                const float* __restrict__ W1,
                                                const float* __restrict__ b1,
                                                const float* __restrict__ W2,
                                                float* __restrict__ ws,
                                                float* __restrict__ out) {
    __shared__ __align__(16) float smem[2 * 32 * 34];
    int blk = blockIdx.x;
    int tid = threadIdx.x;

    if (blk < 64) {
        // ---- S[m,n] = sum_k W1[k,m] W1[k,n], W1 is [128][256] ----
        float* Ai = smem;            // [32][34] : [k][m]
        float* Aj = smem + 1088;
        int m0 = (blk >> 3) * 32, n0 = (blk & 7) * 32;
        int lx = tid & 31, lr = tid >> 5;
        int tx = tid & 15, ty = tid >> 4;
        float a00 = 0, a01 = 0, a10 = 0, a11 = 0;
        for (int kc = 0; kc < 128; kc += 32) {
            #pragma unroll
            for (int i = 0; i < 4; ++i) {
                int k = lr + 8 * i;
                Ai[k * 34 + lx] = W1[(kc + k) * 256 + m0 + lx];
                Aj[k * 34 + lx] = W1[(kc + k) * 256 + n0 + lx];
            }
            __syncthreads();
            #pragma unroll
            for (int k = 0; k < 32; ++k) {
                float2 a = *(const float2*)&Ai[k * 34 + 2 * ty];
                float2 b = *(const float2*)&Aj[k * 34 + 2 * tx];
                a00 += a.x * b.x; a01 += a.x * b.y;
                a10 += a.y * b.x; a11 += a.y * b.y;
            }
            __syncthreads();
        }
        float* S = ws + OFF_S;
        int m = m0 + 2 * ty, n = n0 + 2 * tx;
        S[m * 256 + n]           = a00;
        S[m * 256 + n + 1]       = a01;
        S[(m + 1) * 256 + n]     = a10;
        S[(m + 1) * 256 + n + 1] = a11;
    } else if (blk < 128) {
        // ---- Q[m,n] = sum_j W2[m,j] W2[n,j], W2 is [256][128] ----
        float* Xi = smem;            // [32][34] : [j][m]
        float* Xj = smem + 1088;
        int bq = blk - 64;
        int m0 = (bq >> 3) * 32, n0 = (bq & 7) * 32;
        int lx = tid & 31, lr = tid >> 5;
        int tx = tid & 15, ty = tid >> 4;
        float a00 = 0, a01 = 0, a10 = 0, a11 = 0;
        for (int kc = 0; kc < 128; kc += 32) {
            #pragma unroll
            for (int i = 0; i < 4; ++i) {
                Xi[lx * 34 + lr + 8 * i] = W2[(m0 + lr + 8 * i) * 128 + kc + lx];
                Xj[lx * 34 + lr + 8 * i] = W2[(n0 + lr + 8 * i) * 128 + kc + lx];
            }
            __syncthreads();
            #pragma unroll
            for (int k = 0; k < 32; ++k) {
                float2 a = *(const float2*)&Xi[k * 34 + 2 * ty];
                float2 b = *(const float2*)&Xj[k * 34 + 2 * tx];
                a00 += a.x * b.x; a01 += a.x * b.y;
                a10 += a.y * b.x; a11 += a.y * b.y;
            }
            __syncthreads();
        }
        float* Q = ws + OFF_Q;
        int m = m0 + 2 * ty, n = n0 + 2 * tx;
        Q[m * 256 + n]           = a00;
        Q[m * 256 + n + 1]       = a01;
        Q[(m + 1) * 256 + n]     = a10;
        Q[(m + 1) * 256 + n + 1] = a11;
    } else if (blk < 160) {
        // ---- W2T[c][r] = W2[r][c] ----
        float* tile = smem;  // [32][33]
        int b2 = blk - 128;
        int c0 = (b2 & 3) * 32, r0 = (b2 >> 2) * 32;
        int tx = tid & 31, ty = tid >> 5;
        #pragma unroll
        for (int i = 0; i < 32; i += 8)
            tile[(ty + i) * 33 + tx] = W2[(r0 + ty + i) * 128 + c0 + tx];
        __syncthreads();
        float* W2T = ws + OFF_W2T;
        #pragma unroll
        for (int i = 0; i < 32; i += 8)
            W2T[(c0 + ty + i) * 256 + r0 + tx] = tile[tx * 33 + ty + i];
    } else {
        // ---- per-sample prep ----
        int b = blk - 160;
        float* xs  = smem;
        float* vs  = smem + 128;
        float* red = smem + 256;
        float t = tptr[0];
        float w = 4.f * t * (1.f - t);
        if (tid == 0) ws[OFF_SUM + b] = 0.f;
        if (tid < 128) {
            float dev = state[b * 128 + tid];
            float v   = state[(16 + b) * 128 + tid];
            float xv  = x0[b * 128 + tid] + t * (x1[b * 128 + tid] - x0[b * 128 + tid]) + w * dev;
            xs[tid] = xv;
            vs[tid] = v;
            out[b * 128 + tid] = v;   // first-half output = dev_velocity
            red[tid] = v * v;
        }
        __syncthreads();
        for (int s = 64; s > 0; s >>= 1) {
            if (tid < s) red[tid] += red[tid + s];
            __syncthreads();
        }
        if (tid == 0) ws[OFF_VN + b] = sqrtf(red[0]);

        int m = tid;  // 0..255
        float h = b1[m], uvm = 0.f;
        #pragma unroll 8
        for (int k = 0; k < 128; ++k) {
            float wv = W1[k * 256 + m];    // coalesced
            h   += xs[k] * wv;
            uvm += vs[k] * wv;
        }
        float z  = tanhf(h);
        float dd = 1.f - z * z;
        float cc = -2.f * z * dd;
        const float4* w2r = (const float4*)&W2[m * 128];
        const float4* vs4 = (const float4*)vs;
        float avm = 0.f;
        #pragma unroll 8
        for (int j4 = 0; j4 < 32; ++j4) {
            float4 ww = w2r[j4];
            float4 vv = vs4[j4];
            avm += ww.x * vv.x + ww.y * vv.y + ww.z * vv.z + ww.w * vv.w;
        }
        ws[OFF_D  + b * 256 + m] = dd;
        ws[OFF_C  + b * 256 + m] = cc;
        ws[OFF_UV + b * 256 + m] = uvm;
        ws[OFF_AV + b * 256 + m] = avm;
    }
}

// =====================================================================
// P = S diag(d) W2. 256-thr blocks, 32m x 64j tile, 4x2 per thread.
// grid (2 jt, 8 mt, 16 b). Writes PT[b][j][m] and Pn[b][m][j].
// =====================================================================
__global__ __launch_bounds__(256) void k_pmat3(const float* __restrict__ Smat,
                                               const float* __restrict__ dall,
                                               const float* __restrict__ W2,
                                               float* __restrict__ PT,
                                               float* __restrict__ Pn) {
    __shared__ __align__(16) float ST[32 * 36];  // [n][m-local]
    __shared__ __align__(16) float YT[32 * 68];  // [n][j-local]
    int b = blockIdx.z, mt = blockIdx.y, jt = blockIdx.x;
    int m0 = mt * 32, j0 = jt * 64;
    const float* dvec = dall + b * 256;
    int tid = threadIdx.x;
    int n = tid >> 3, c4 = (tid & 7) * 4;    // staging
    int ty = tid >> 5, tx = tid & 31;        // compute: 4m x 2j
    float acc[4][2] = {};
    for (int nc = 0; nc < 256; nc += 32) {
        // S symmetric: S[m,n] = S[n,m] -> coalesced row reads
        *(float4*)&ST[n * 36 + c4] = *(const float4*)&Smat[(nc + n) * 256 + m0 + c4];
        float dn = dvec[nc + n];
        #pragma unroll
        for (int i = 0; i < 2; ++i) {
            int col = c4 + 32 * i;
            float4 wv = *(const float4*)&W2[(nc + n) * 128 + j0 + col];
            wv.x *= dn; wv.y *= dn; wv.z *= dn; wv.w *= dn;
            *(float4*)&YT[n * 68 + col] = wv;
        }
        __syncthreads();
        #pragma unroll 8
        for (int k = 0; k < 32; ++k) {
            float4 a  = *(const float4*)&ST[k * 36 + 4 * ty];
            float2 bb = *(const float2*)&YT[k * 68 + 2 * tx];
            acc[0][0] += a.x * bb.x; acc[0][1] += a.x * bb.y;
            acc[1][0] += a.y * bb.x; acc[1][1] += a.y * bb.y;
            acc[2][0] += a.z * bb.x; acc[2][1] += a.z * bb.y;
            acc[3][0] += a.w * bb.x; acc[3][1] += a.w * bb.y;
        }
        __syncthreads();
    }
    float* ptb = PT + b * 32768;
    float* pnb = Pn + b * 32768;
    #pragma unroll
    for (int jj = 0; jj < 2; ++jj) {
        float4 v = make_float4(acc[0][jj], acc[1][jj], acc[2][jj], acc[3][jj]);
        *(float4*)&ptb[(j0 + 2 * tx + jj) * 256 + m0 + 4 * ty] = v;
    }
    #pragma unroll
    for (int ii = 0; ii < 4; ++ii) {
        float2 v = make_float2(acc[ii][0], acc[ii][1]);
        *(float2*)&pnb[(m0 + 4 * ty + ii) * 128 + j0 + 2 * tx] = v;
    }
}

// =====================================================================
// Frobenius-norm partials. 256-thr blocks (4 waves split j=128),
// triangular (mi,mj) tiles, grid (36,16). LDS-staged; stride-49
// conflict-free cross-wave reduction.
// =====================================================================
__global__ __launch_bounds__(256) void k_fnorm5(const float* __restrict__ PT,
                                                const float* __restrict__ W2T,
                                                const float* __restrict__ Smat,
                                                const float* __restrict__ Qmat,
                                                const float* __restrict__ call,
                                                float* __restrict__ sums) {
    __shared__ __align__(16) float lds[16384];  // 64 KB, re-purposed
    int b = blockIdx.y;
    int idx = blockIdx.x;
    int tj = 0;
    while ((tj + 1) * (tj + 2) / 2 <= idx) ++tj;
    int ti = idx - tj * (tj + 1) / 2;      // ti <= tj
    int mi0 = ti * 32, mj0 = tj * 32;
    int tid = threadIdx.x;
    float* PiT = lds;              // [128][32]
    float* PjT = lds + 4096;
    float* WiT = lds + 8192;
    float* WjT = lds + 12288;
    const float* ptb = PT + b * 32768;
    int jr = tid >> 3, jc4 = (tid & 7) * 4;
    #pragma unroll
    for (int it = 0; it < 4; ++it) {
        int j = jr + 32 * it;
        *(float4*)&PiT[j * 32 + jc4] = *(const float4*)&ptb[j * 256 + mi0 + jc4];
        *(float4*)&PjT[j * 32 + jc4] = *(const float4*)&ptb[j * 256 + mj0 + jc4];
        *(float4*)&WiT[j * 32 + jc4] = *(const float4*)&W2T[j * 256 + mi0 + jc4];
        *(float4*)&WjT[j * 32 + jc4] = *(const float4*)&W2T[j * 256 + mj0 + jc4];
    }
    __syncthreads();
    int w = tid >> 6, s = tid & 63;
    int ty = s >> 3, tx = s & 7;
    float r[4][4] = {}, f[4][4] = {}, g[4][4] = {};
    int jbase = 32 * w;
    #pragma unroll 4
    for (int jj = 0; jj < 32; ++jj) {
        int j = jbase + jj;
        float4 pi4 = *(const float4*)&PiT[j * 32 + 4 * ty];
        float4 pj4 = *(const float4*)&PjT[j * 32 + 4 * tx];
        float4 wi4 = *(const float4*)&WiT[j * 32 + 4 * ty];
        float4 wj4 = *(const float4*)&WjT[j * 32 + 4 * tx];
        float pi[4] = {pi4.x, pi4.y, pi4.z, pi4.w};
        float pj[4] = {pj4.x, pj4.y, pj4.z, pj4.w};
        float wi[4] = {wi4.x, wi4.y, wi4.z, wi4.w};
        float wj[4] = {wj4.x, wj4.y, wj4.z, wj4.w};
        #pragma unroll
        for (int ii = 0; ii < 4; ++ii)
            #pragma unroll
            for (int kk = 0; kk < 4; ++kk) {
                r[ii][kk] += pi[ii] * pj[kk];   // R[mi,mj]
                f[ii][kk] += pi[ii] * wj[kk];   // M[mi,mj]
                g[ii][kk] += pj[kk] * wi[ii];   // M[mj,mi]
            }
    }
    __syncthreads();   // done with tiles; alias lds as reduction scratch
    {
        // stride 49 (odd) -> (tid*49+k) mod 32 covers all banks; <=2 lanes/bank
        float* scr = lds;
        int base = tid * 49;
        #pragma unroll
        for (int ii = 0; ii < 4; ++ii)
            #pragma unroll
            for (int kk = 0; kk < 4; ++kk) {
                scr[base + ii * 4 + kk]      = r[ii][kk];
                scr[base + 16 + ii * 4 + kk] = f[ii][kk];
                scr[base + 32 + ii * 4 + kk] = g[ii][kk];
            }
    }
    __syncthreads();
    if (tid < 64) {
        const float* scr = lds;
        float tr[16], tf[16], tg[16];
        #pragma unroll
        for (int k = 0; k < 16; ++k) {
            tr[k] = scr[tid * 49 + k]           + scr[(tid + 64) * 49 + k]
                  + scr[(tid + 128) * 49 + k]   + scr[(tid + 192) * 49 + k];
            tf[k] = scr[tid * 49 + 16 + k]      + scr[(tid + 64) * 49 + 16 + k]
                  + scr[(tid + 128) * 49 + 16 + k] + scr[(tid + 192) * 49 + 16 + k];
            tg[k] = scr[tid * 49 + 32 + k]      + scr[(tid + 64) * 49 + 32 + k]
                  + scr[(tid + 128) * 49 + 32 + k] + scr[(tid + 192) * 49 + 32 + k];
        }
        const float* cb = call + b * 256;
        int mi = mi0 + 4 * (tid >> 3), mj = mj0 + 4 * (tid & 7);
        float4 ce4 = *(const float4*)&cb[mj];
        float ce[4] = {ce4.x, ce4.y, ce4.z, ce4.w};
        float sum = 0.f;
        #pragma unroll
        for (int ii = 0; ii < 4; ++ii) {
            float ci = cb[mi + ii];
            float4 S4 = *(const float4*)&Smat[(mi + ii) * 256 + mj];
            float4 Q4 = *(const float4*)&Qmat[(mi + ii) * 256 + mj];
            float Sv[4] = {S4.x, S4.y, S4.z, S4.w};
            float Qv[4] = {Q4.x, Q4.y, Q4.z, Q4.w};
            #pragma unroll
            for (int kk = 0; kk < 4; ++kk)
                sum += ci * ce[kk] * Sv[kk] * (Qv[kk] * tr[ii * 4 + kk] + tf[ii * 4 + kk] * tg[ii * 4 + kk]);
        }
        if (ti < tj) sum *= 2.f;
        #pragma unroll
        for (int off = 32; off > 0; off >>= 1)
            sum += __shfl_down(sum, off);
        if (tid == 0) atomicAdd(&sums[b], sum);
    }
}

// =====================================================================
// Final: nrm, pv, g1/g2, second-half output. 16 blocks x 256 thr.
// =====================================================================
__global__ __launch_bounds__(256) void k_fin3(const float* __restrict__ state,
                                              const float* __restrict__ W2,
                                              float* __restrict__ ws,
                                              float* __restrict__ out) {
    int b = blockIdx.x;
    int tid = threadIdx.x;
    __shared__ float vs[128], g1[256], g2[256], red[256];
    __shared__ float snrm;
    if (tid < 128) vs[tid] = state[(16 + b) * 128 + tid];
    if (tid == 0) {
        float tot = atomicAdd(&ws[OFF_SUM + b], 0.0f);  // coherent read
        snrm = sqrtf(fmaxf(2.f * tot, 0.f));
    }
    __syncthreads();

    const float* ptb = ws + OFF_PT + b * 32768;
    const float* pnb = ws + OFF_PN + b * 32768;
    int m = tid;
    float pv = 0.f;
    #pragma unroll 8
    for (int j = 0; j < 128; ++j)
        pv += ptb[j * 256 + m] * vs[j];     // coalesced over m
    float cc  = ws[OFF_C  + b * 256 + m];
    float uvm = ws[OFF_UV + b * 256 + m];
    float avm = ws[OFF_AV + b * 256 + m];
    g1[m] = cc * pv  * uvm;
    g2[m] = cc * avm * uvm;
    __syncthreads();

    // raw_i = sum_mm W2[mm,i] g1[mm] + Pn[mm,i] g2[mm]; mm split over 2 halves
    int i = tid & 127, half = tid >> 7;
    int mmlo = half * 128;
    float raw = 0.f;
    #pragma unroll 8
    for (int mm = mmlo; mm < mmlo + 128; ++mm)
        raw += W2[mm * 128 + i] * g1[mm] + pnb[mm * 128 + i] * g2[mm];  // both coalesced
    red[tid] = raw;
    __syncthreads();
    if (tid < 128) {
        float rawt = red[tid] + red[tid + 128];
        float vn = ws[OFF_VN + b];
        float a  = -0.5f * rawt / ((snrm + 1e-6f) * (vn + 1e-6f));
        out[(16 + b) * 128 + tid] = a - 0.1f * state[b * 128 + tid];
    }
}

extern "C" void kernel_launch(void* const* d_in, const int* in_sizes, int n_in,
                              void* d_out, int out_size, void* d_ws, size_t ws_size,
                              hipStream_t stream) {
    (void)in_sizes; (void)n_in; (void)out_size; (void)ws_size;
    const float* t     = (const float*)d_in[0];
    const float* state = (const float*)d_in[1];
    const float* x0    = (const float*)d_in[2];
    const float* x1    = (const float*)d_in[3];
    const float* W1    = (const float*)d_in[4];
    const float* b1    = (const float*)d_in[5];
    const float* W2    = (const float*)d_in[6];
    // b2 cancels in the Jacobian — unused.
    float* out = (float*)d_out;
    float* ws  = (float*)d_ws;

    k_stage1<<<176, 256, 0, stream>>>(t, state, x0, x1, W1, b1, W2, ws, out);
    k_pmat3<<<dim3(2, 8, 16), 256, 0, stream>>>(ws + OFF_S, ws + OFF_D, W2,
                                                ws + OFF_PT, ws + OFF_PN);
    k_fnorm5<<<dim3(36, 16), 256, 0, stream>>>(ws + OFF_PT, ws + OFF_W2T, ws + OFF_S,
                                               ws + OFF_Q, ws + OFF_C, ws + OFF_SUM);
    k_fin3<<<16, 256, 0, stream>>>(state, W2, ws, out);
}